// Round 20
// baseline (81.041 us; speedup 1.0000x reference)
//
#include <hip/hip_runtime.h>
#include <hip/hip_bf16.h>

typedef __bf16 bf16x8 __attribute__((ext_vector_type(8)));
typedef float f32x4 __attribute__((ext_vector_type(4)));
typedef ushort us8 __attribute__((ext_vector_type(8)));

#define MFMA(a, b, c) __builtin_amdgcn_mfma_f32_16x16x32_bf16((a), (b), (c), 0, 0, 0)

static constexpr int T_LEN = 2048;
static constexpr int C_DIM = 1024;
static constexpr int H_DIM = 128;
static constexpr int M_ROWS = 8 * 2048;    // 16384
static constexpr int N_COLS = 384;         // 3 * 128
static constexpr int SLOTS_PER_B = 528;    // partial slots (qi>=32)
static constexpr int PSTR = 72;            // P buffer row stride
static constexpr int KSTR = 136;           // K LDS row stride (272B, 2-way max)
static constexpr int VSTR = 72;            // V LDS row stride (144B, 2-way max)

__device__ __forceinline__ ushort f2bf(float f) {
  union { float f; unsigned u; } v; v.f = f;
  unsigned u = v.u;
  u += 0x7fffu + ((u >> 16) & 1u);
  return (ushort)(u >> 16);
}
__device__ __forceinline__ float bf2f(ushort u) {
  union { unsigned u; float f; } v; v.u = (unsigned)u << 16;
  return v.f;
}

// raw barrier: lgkmcnt(0) for LDS visibility, NO vmcnt drain.
__device__ __forceinline__ void waitbar() {
  asm volatile("s_waitcnt lgkmcnt(0)" ::: "memory");
  __builtin_amdgcn_s_barrier();
  __builtin_amdgcn_sched_barrier(0);
}

// G4-standard swizzle for 128B rows (r17/r19-proven, 0 conflicts measured):
__device__ __forceinline__ int sw128(int row, int slot) {
  return row * 128 + ((slot * 16) ^ ((row & 7) << 4));
}

// ---------------------------------------------------------------------------
// Kernel 0: Wq/Wk/Wv fp32 [1024][128] -> bf16 wt, FRAGMENT-LINEAR per
// (kt, half): wt[((kt*2+half)*24 + fs)*512 + lane*8 + j] holds
//   B col gc = half*192 + (fs%12)*16 + (lane&15),
//   k      c = kt*64 + (fs/12)*32 + (lane>>4)*8 + j.
// A wave's B-fragment = ONE contiguous 1 KB read (L2-resident).
// ---------------------------------------------------------------------------
__global__ void wt_convert(const float* __restrict__ Wq,
                           const float* __restrict__ Wk,
                           const float* __restrict__ Wv,
                           ushort* __restrict__ wt) {
  int o = blockIdx.x * 256 + threadIdx.x;   // 0..393215
  int kthalf = o / 12288;                    // 0..31
  int rem = o - kthalf * 12288;
  int fs = rem >> 9;                         // 0..23
  int li = rem & 511;
  int lane = li >> 3, j = li & 7;
  int kt = kthalf >> 1, half = kthalf & 1;
  int kk = fs / 12, cg = fs - kk * 12;
  int gc = half * 192 + cg * 16 + (lane & 15);
  int c  = kt * 64 + kk * 32 + (lane >> 4) * 8 + j;
  int mat = gc >> 7, h = gc & 127;
  const float* W = (mat == 0) ? Wq : ((mat == 1) ? Wk : Wv);
  wt[o] = f2bf(W[c * H_DIM + h]);
}

// ---------------------------------------------------------------------------
// Kernel 1: fused QKV projection v11 — LDS-BW relief: B fragments loaded
// INLINE from global (fragment-linear wt, 1 KB contiguous, L2-resident),
// A via r19's LDS path (sw128, E/O distance-2, raw barrier). LDS = 16 KB
// (A dbuf only). B rides the L2 path in parallel with LDS + MFMA.
// BM=64, BN=192, BK=64 -> 512 blocks, 16 iters, 24 MFMA/wave/iter.
// ---------------------------------------------------------------------------
__global__ __launch_bounds__(256, 2) void qkv_gemm(const float* __restrict__ X,
                                                   const ushort* __restrict__ wt,
                                                   ushort* __restrict__ qws,
                                                   ushort* __restrict__ kws,
                                                   ushort* __restrict__ vtws) {
  __shared__ ushort As[2][64 * 64];    // [64][64] sw128, 8 KB each
  const int tid = threadIdx.x;
  const int wid = tid >> 6, lane = tid & 63;
  const int lg = lane >> 4, lr = lane & 15;
  const int m0 = (blockIdx.x >> 1) * 64;
  const int n0h = blockIdx.x & 1;
  const int n0 = n0h * 192;
  const float QSCL = 0.03125f * 1.44269504f;

  // A staging (r19): row=tid>>3 (0..31) and +32; 8 floats at (tid&7)*8
  const int arow = tid >> 3, aslot = tid & 7;
  const float* gA0 = &X[(size_t)(m0 + arow) * C_DIM + aslot * 8];
  const float* gA1 = gA0 + (size_t)32 * C_DIM;
  const int awb0 = sw128(arow, aslot);          // +4096 for row+32

  // A fragment read bases: + r*2048 for r=0..3
  const int afb0 = sw128(lr, lg), afb1 = sw128(lr, 4 + lg);

  // B fragment base (per-lane): fragment (kt, kk, c) at
  //   wt + ((kt*2+n0h)*24 + kk*12 + wid*3 + c)*512 + lane*8
  const ushort* wB = wt + (size_t)lane * 8 + (size_t)(wid * 3) * 512;

  f32x4 acc[4][3];
#pragma unroll
  for (int r = 0; r < 4; ++r)
#pragma unroll
    for (int c = 0; c < 3; ++c)
      acc[r][c] = f32x4{0.f, 0.f, 0.f, 0.f};

  float4 aE[4], aO[4];

#define LOAD_A(aS, kt_)                                                    \
  {                                                                        \
    aS[0] = *(const float4*)(gA0 + (kt_) * 64);                            \
    aS[1] = *(const float4*)(gA0 + (kt_) * 64 + 4);                        \
    aS[2] = *(const float4*)(gA1 + (kt_) * 64);                            \
    aS[3] = *(const float4*)(gA1 + (kt_) * 64 + 4);                        \
  }
#define WRITE_A(aS, buf)                                                   \
  {                                                                        \
    us8 av0, av1;                                                          \
    av0[0] = f2bf(aS[0].x); av0[1] = f2bf(aS[0].y);                        \
    av0[2] = f2bf(aS[0].z); av0[3] = f2bf(aS[0].w);                        \
    av0[4] = f2bf(aS[1].x); av0[5] = f2bf(aS[1].y);                        \
    av0[6] = f2bf(aS[1].z); av0[7] = f2bf(aS[1].w);                        \
    av1[0] = f2bf(aS[2].x); av1[1] = f2bf(aS[2].y);                        \
    av1[2] = f2bf(aS[2].z); av1[3] = f2bf(aS[2].w);                        \
    av1[4] = f2bf(aS[3].x); av1[5] = f2bf(aS[3].y);                        \
    av1[6] = f2bf(aS[3].z); av1[7] = f2bf(aS[3].w);                        \
    *(us8*)((char*)&As[buf][0] + awb0) = av0;                              \
    *(us8*)((char*)&As[buf][0] + awb0 + 4096) = av1;                       \
  }
#define COMPUTE(buf, kt_)                                                  \
  {                                                                        \
    const ushort* wBk = wB + (size_t)(((kt_) * 2 + n0h) * 24) * 512;       \
    _Pragma("unroll")                                                      \
    for (int kk = 0; kk < 2; ++kk) {                                       \
      const int afb = kk ? afb1 : afb0;                                    \
      bf16x8 b0 = *(const bf16x8*)(wBk + (size_t)(kk * 12) * 512);         \
      bf16x8 b1 = *(const bf16x8*)(wBk + (size_t)(kk * 12 + 1) * 512);     \
      bf16x8 b2 = *(const bf16x8*)(wBk + (size_t)(kk * 12 + 2) * 512);     \
      bf16x8 a0 = *(const bf16x8*)((const char*)&As[buf][0] + afb);        \
      bf16x8 a1 = *(const bf16x8*)((const char*)&As[buf][0] + afb + 2048); \
      bf16x8 a2 = *(const bf16x8*)((const char*)&As[buf][0] + afb + 4096); \
      bf16x8 a3 = *(const bf16x8*)((const char*)&As[buf][0] + afb + 6144); \
      acc[0][0] = MFMA(a0, b0, acc[0][0]);                                 \
      acc[1][0] = MFMA(a1, b0, acc[1][0]);                                 \
      acc[2][0] = MFMA(a2, b0, acc[2][0]);                                 \
      acc[3][0] = MFMA(a3, b0, acc[3][0]);                                 \
      acc[0][1] = MFMA(a0, b1, acc[0][1]);                                 \
      acc[1][1] = MFMA(a1, b1, acc[1][1]);                                 \
      acc[2][1] = MFMA(a2, b1, acc[2][1]);                                 \
      acc[3][1] = MFMA(a3, b1, acc[3][1]);                                 \
      acc[0][2] = MFMA(a0, b2, acc[0][2]);                                 \
      acc[1][2] = MFMA(a1, b2, acc[1][2]);                                 \
      acc[2][2] = MFMA(a2, b2, acc[2][2]);                                 \
      acc[3][2] = MFMA(a3, b2, acc[3][2]);                                 \
    }                                                                      \
  }

  // ---- prologue: A(0) -> buf0; A(1)->E, A(2)->O ----
  {
    float4 aT[4];
    LOAD_A(aT, 0);
    WRITE_A(aT, 0);
  }
  LOAD_A(aE, 1);
  LOAD_A(aO, 2);
  waitbar();   // tile0 staged & visible

  for (int k2 = 0; k2 < 16; k2 += 2) {
    // ==== even iter kt=k2: write A(k2+1) -> buf1; compute buf0 ====
    WRITE_A(aE, 1);
    if (k2 + 3 < 16) LOAD_A(aE, k2 + 3);
    COMPUTE(0, k2);
    waitbar();

    // ==== odd iter kt=k2+1: write A(k2+2) -> buf0; compute buf1 ====
    if (k2 + 2 < 16) WRITE_A(aO, 0);
    if (k2 + 4 < 16) LOAD_A(aO, k2 + 4);
    COMPUTE(1, k2 + 1);
    waitbar();
  }
#undef LOAD_A
#undef WRITE_A
#undef COMPUTE

  // epilogue: C frag layout col=lane&15, row=(lane>>4)*4+j
#pragma unroll
  for (int c = 0; c < 3; ++c) {
    int gc = n0 + wid * 48 + c * 16 + lr;
    int mat = gc >> 7, h = gc & 127;
#pragma unroll
    for (int r = 0; r < 4; ++r) {
#pragma unroll
      for (int j = 0; j < 4; ++j) {
        int gr = m0 + r * 16 + lg * 4 + j;
        float val = acc[r][c][j];
        ushort ov = f2bf(mat == 0 ? val * QSCL : val);
        if (mat == 0) {
          qws[(size_t)gr * H_DIM + h] = ov;
        } else if (mat == 1) {
          kws[(size_t)gr * H_DIM + h] = ov;
        } else {
          int b = gr >> 11, t = gr & 2047;
          vtws[((size_t)b * H_DIM + h) * T_LEN + t] = ov;
        }
      }
    }
  }
}

// ---------------------------------------------------------------------------
// Kernel 2a: flash partial pass, block-cooperative LDS-staged K/V
// (unchanged from round 9).
// ---------------------------------------------------------------------------
__global__ __launch_bounds__(256, 3) void attn_part(const ushort* __restrict__ qws,
                                                    const ushort* __restrict__ kws,
                                                    const ushort* __restrict__ vtws,
                                                    float* __restrict__ pml,
                                                    ushort* __restrict__ pacc,
                                                    float* __restrict__ out) {
  __shared__ ushort Klds[64 * KSTR];
  __shared__ ushort Vlds[128 * VSTR];
  __shared__ ushort Pw[4][16 * PSTR];

  const int tid = threadIdx.x;
  const int wid = tid >> 6, lane = tid & 63;
  const int lg = lane >> 4, lr = lane & 15;
  const int bid = blockIdx.x;
  const int b = bid & 7;
  const int item = bid >> 3;

  int qb, ck;
  bool direct;
  if (item < 8) {
    qb = item; ck = 0; direct = true;
  } else {
    const int p = item - 8;
    direct = false;
    if (p < 12)      { int q = p / 3;        qb = 8 + q;  ck = p - q * 3; }
    else if (p < 28) { int q = (p - 12) >> 2; qb = 12 + q; ck = (p - 12) & 3; }
    else if (p < 48) { int q = (p - 28) / 5; qb = 16 + q; ck = (p - 28) - q * 5; }
    else if (p < 72) { int q = (p - 48) / 6; qb = 20 + q; ck = (p - 48) - q * 6; }
    else if (p < 100){ int q = (p - 72) / 7; qb = 24 + q; ck = (p - 72) - q * 7; }
    else             { int q = (p - 100) >> 3; qb = 28 + q; ck = (p - 100) & 7; }
  }
  const int qi = qb * 4 + wid;
  const int q0 = qi * 16;
  const int nt = qb + 1;
  const int kvt_lo = direct ? 0 : ck * 4;
  const int kvt_hi = direct ? nt : min(ck * 4 + 4, nt);
  const size_t tokbase = (size_t)b * T_LEN;
  const ushort* vb = vtws + (size_t)b * H_DIM * T_LEN;

  const int kr = tid >> 2, kseg = tid & 3;
  const int vr = tid >> 1, vseg = tid & 1;
  const ushort* gK = &kws[(tokbase + kr) * H_DIM + kseg * 32];
  const ushort* gV = &vb[(size_t)vr * T_LEN + vseg * 32];

  bf16x8 qf[4];
#pragma unroll
  for (int hk = 0; hk < 4; ++hk)
    qf[hk] = *(const bf16x8*)&qws[(tokbase + q0 + lr) * H_DIM + hk * 32 + lg * 8];

  f32x4 acc[8];
#pragma unroll
  for (int hf = 0; hf < 8; ++hf) acc[hf] = f32x4{0.f, 0.f, 0.f, 0.f};
  float mrun = -INFINITY, lrun = 0.f;

  ushort* Pme = &Pw[wid][0];

  us8 kreg[4], vreg[4];
#pragma unroll
  for (int i = 0; i < 4; ++i) {
    kreg[i] = *(const us8*)(gK + (size_t)kvt_lo * 64 * H_DIM + i * 8);
    vreg[i] = *(const us8*)(gV + kvt_lo * 64 + i * 8);
  }

  for (int kvt = kvt_lo; kvt < kvt_hi; ++kvt) {
    const int kv0 = kvt * 64;

    __syncthreads();
#pragma unroll
    for (int i = 0; i < 4; ++i) {
      *(us8*)&Klds[kr * KSTR + kseg * 32 + i * 8] = kreg[i];
      *(us8*)&Vlds[vr * VSTR + vseg * 32 + i * 8] = vreg[i];
    }
    if (kvt + 1 < kvt_hi) {
#pragma unroll
      for (int i = 0; i < 4; ++i) {
        kreg[i] = *(const us8*)(gK + (size_t)(kv0 + 64) * H_DIM + i * 8);
        vreg[i] = *(const us8*)(gV + kv0 + 64 + i * 8);
      }
    }
    __syncthreads();

    f32x4 s[4];
#pragma unroll
    for (int c = 0; c < 4; ++c) {
      f32x4 sc = f32x4{0.f, 0.f, 0.f, 0.f};
#pragma unroll
      for (int hk = 0; hk < 4; ++hk) {
        bf16x8 kf = *(const bf16x8*)&Klds[(c * 16 + lr) * KSTR + hk * 32 + lg * 8];
        sc = MFMA(kf, qf[hk], sc);
      }
      s[c] = sc;
    }

    if (kvt == nt - 1) {
#pragma unroll
      for (int c = 0; c < 4; ++c)
#pragma unroll
        for (int j = 0; j < 4; ++j) {
          int kv = kv0 + c * 16 + lg * 4 + j;
          if (kv > q0 + lr) s[c][j] = -INFINITY;
        }
    }

    float mx = s[0][0];
#pragma unroll
    for (int c = 0; c < 4; ++c)
#pragma unroll
      for (int j = 0; j < 4; ++j) mx = fmaxf(mx, s[c][j]);
    mx = fmaxf(mx, __shfl_xor(mx, 16));
    mx = fmaxf(mx, __shfl_xor(mx, 32));

    float mnew = fmaxf(mrun, mx);
    float scold = exp2f(mrun - mnew);

    float rsum = 0.f;
#pragma unroll
    for (int c = 0; c < 4; ++c)
#pragma unroll
      for (int j = 0; j < 4; ++j) {
        float p = exp2f(s[c][j] - mnew);
        s[c][j] = p;
        rsum += p;
      }

#pragma unroll
    for (int c = 0; c < 4; ++c) {
      ushort4 u;
      u.x = f2bf(s[c][0]); u.y = f2bf(s[c][1]);
      u.z = f2bf(s[c][2]); u.w = f2bf(s[c][3]);
      *(ushort4*)&Pme[lr * PSTR + c * 16 + lg * 4] = u;
    }

    bf16x8 v0[8];
#pragma unroll
    for (int hf = 0; hf < 8; ++hf)
      v0[hf] = *(const bf16x8*)&Vlds[(hf * 16 + lr) * VSTR + lg * 8];

    rsum += __shfl_xor(rsum, 16);
    rsum += __shfl_xor(rsum, 32);

    lrun = lrun * scold + rsum;
    mrun = mnew;
#pragma unroll
    for (int hf = 0; hf < 8; ++hf)
#pragma unroll
      for (int j = 0; j < 4; ++j) acc[hf][j] *= scold;

    bf16x8 pa0 = *(const bf16x8*)&Pme[lr * PSTR + lg * 8];
    bf16x8 pa1 = *(const bf16x8*)&Pme[lr * PSTR + 32 + lg * 8];

#pragma unroll
    for (int hf = 0; hf < 8; ++hf)
      acc[hf] = MFMA(v0[hf], pa0, acc[hf]);
#pragma unroll
    for (int hf = 0; hf < 8; ++hf) {
      bf16x8 v1 = *(const bf16x8*)&Vlds[(hf * 16 + lr) * VSTR + 32 + lg * 8];
      acc[hf] = MFMA(v1, pa1, acc[hf]);
    }
  }

  if (direct) {
    float inv = 1.0f / lrun;
    float* op = &out[(tokbase + q0 + lr) * H_DIM + lg * 4];
#pragma unroll
    for (int hf = 0; hf < 8; ++hf) {
      float4 r0 = make_float4(acc[hf][0] * inv, acc[hf][1] * inv,
                              acc[hf][2] * inv, acc[hf][3] * inv);
      *(float4*)(op + hf * 16) = r0;
    }
  } else {
    int base;
    if (qi < 48)       base = (qi - 32) * 3;
    else if (qi < 64)  base = 48 + (qi - 48) * 4;
    else if (qi < 80)  base = 112 + (qi - 64) * 5;
    else if (qi < 96)  base = 192 + (qi - 80) * 6;
    else if (qi < 112) base = 288 + (qi - 96) * 7;
    else               base = 400 + (qi - 112) * 8;
    const size_t slot = (size_t)b * SLOTS_PER_B + base + ck;
    if (lg == 0) {
      pml[slot * 32 + lr] = mrun;
      pml[slot * 32 + 16 + lr] = lrun;
    }
    ushort* ap = &pacc[slot * 2048 + (size_t)lr * 128 + lg * 4];
#pragma unroll
    for (int hf = 0; hf < 8; ++hf) {
      ushort4 u;
      u.x = f2bf(acc[hf][0]); u.y = f2bf(acc[hf][1]);
      u.z = f2bf(acc[hf][2]); u.w = f2bf(acc[hf][3]);
      *(ushort4*)(ap + hf * 16) = u;
    }
  }
}

// ---------------------------------------------------------------------------
// Kernel 2b: online merge of 3..8 partials per (b, qi) for qi >= 32.
// (unchanged)
// ---------------------------------------------------------------------------
__global__ __launch_bounds__(256) void attn_merge(const float* __restrict__ pml,
                                                  const ushort* __restrict__ pacc,
                                                  float* __restrict__ out) {
  const int bid = blockIdx.x;
  const int b = bid & 7, qi = (bid >> 3) + 32;
  int base, nch;
  if (qi < 48)       { base = (qi - 32) * 3;        nch = 3; }
  else if (qi < 64)  { base = 48 + (qi - 48) * 4;   nch = 4; }
  else if (qi < 80)  { base = 112 + (qi - 64) * 5;  nch = 5; }
  else if (qi < 96)  { base = 192 + (qi - 80) * 6;  nch = 6; }
  else if (qi < 112) { base = 288 + (qi - 96) * 7;  nch = 7; }
  else               { base = 400 + (qi - 112) * 8; nch = 8; }
  const size_t slot0 = (size_t)b * SLOTS_PER_B + base;
  const int tid = threadIdx.x;
  const int r = tid >> 4, c0 = (tid & 15) * 8;

  float mrun = -INFINITY, L = 0.f;
  float o[8];
#pragma unroll
  for (int i = 0; i < 8; ++i) o[i] = 0.f;

  for (int ck = 0; ck < nch; ++ck) {
    const size_t s = slot0 + ck;
    float m = pml[s * 32 + r];
    float l = pml[s * 32 + 16 + r];
    float mn = fmaxf(mrun, m);
    float sc = exp2f(mrun - mn);
    float w  = exp2f(m - mn);
    L = L * sc + w * l;
    const ushort* ap = &pacc[s * 2048 + (size_t)r * 128 + c0];
    ushort4 u0 = *(const ushort4*)ap;
    ushort4 u1 = *(const ushort4*)(ap + 4);
    o[0] = o[0] * sc + w * bf2f(u0.x); o[1] = o[1] * sc + w * bf2f(u0.y);
    o[2] = o[2] * sc + w * bf2f(u0.z); o[3] = o[3] * sc + w * bf2f(u0.w);
    o[4] = o[4] * sc + w * bf2f(u1.x); o[5] = o[5] * sc + w * bf2f(u1.y);
    o[6] = o[6] * sc + w * bf2f(u1.z); o[7] = o[7] * sc + w * bf2f(u1.w);
    mrun = mn;
  }
  float invL = 1.0f / L;
  float4 r0 = make_float4(o[0] * invL, o[1] * invL, o[2] * invL, o[3] * invL);
  float4 r1 = make_float4(o[4] * invL, o[5] * invL, o[6] * invL, o[7] * invL);
  float* op = &out[((size_t)b * T_LEN + qi * 16 + r) * H_DIM + c0];
  *(float4*)op = r0;
  *(float4*)(op + 4) = r1;
}

// ---------------------------------------------------------------------------
// ws layout identical to rounds 8-19 (total 30,670,848 B, proven fit):
//   [0, 786432) wt (dead after qkv_gemm; pml overlaps, 540,672 B)
//   qws / kws / vtws ; pacc = 8*528 slots * 2048 bf16
// ---------------------------------------------------------------------------
extern "C" void kernel_launch(void* const* d_in, const int* in_sizes, int n_in,
                              void* d_out, int out_size, void* d_ws, size_t ws_size,
                              hipStream_t stream) {
  const float* emb = (const float*)d_in[0];
  const float* Wq  = (const float*)d_in[1];
  const float* Wk  = (const float*)d_in[2];
  const float* Wv  = (const float*)d_in[3];
  float* out = (float*)d_out;

  ushort* wt   = (ushort*)d_ws;
  ushort* qws  = wt  + (size_t)N_COLS * C_DIM;
  ushort* kws  = qws + (size_t)M_ROWS * H_DIM;
  ushort* vtws = kws + (size_t)M_ROWS * H_DIM;
  ushort* pacc = vtws + (size_t)8 * H_DIM * T_LEN;
  float*  pml  = (float*)d_ws;   // overlaps dead wt region

  wt_convert<<<(N_COLS * C_DIM) / 256, 256, 0, stream>>>(Wq, Wk, Wv, wt);
  qkv_gemm<<<(M_ROWS / 64) * 2, 256, 0, stream>>>(emb, wt, qws, kws, vtws);
  attn_part<<<8 * 140, 256, 0, stream>>>(qws, kws, vtws, pml, pacc, out);
  attn_merge<<<8 * 96, 256, 0, stream>>>(pml, pacc, out);
}

// Round 21
// 79.474 us; speedup vs baseline: 1.0197x; 1.0197x over previous
//
#include <hip/hip_runtime.h>
#include <hip/hip_bf16.h>

typedef __bf16 bf16x8 __attribute__((ext_vector_type(8)));
typedef float f32x4 __attribute__((ext_vector_type(4)));
typedef ushort us8 __attribute__((ext_vector_type(8)));

#define MFMA(a, b, c) __builtin_amdgcn_mfma_f32_16x16x32_bf16((a), (b), (c), 0, 0, 0)

static constexpr int T_LEN = 2048;
static constexpr int C_DIM = 1024;
static constexpr int H_DIM = 128;
static constexpr int M_ROWS = 8 * 2048;    // 16384
static constexpr int N_COLS = 384;         // 3 * 128
static constexpr int SLOTS_PER_B = 528;    // partial slots (qi>=32)
static constexpr int PSTR = 72;            // P buffer row stride
static constexpr int KSTR = 136;           // K LDS row stride (272B, 2-way max)
static constexpr int VSTR = 72;            // V LDS row stride (144B, 2-way max)

__device__ __forceinline__ ushort f2bf(float f) {
  union { float f; unsigned u; } v; v.f = f;
  unsigned u = v.u;
  u += 0x7fffu + ((u >> 16) & 1u);
  return (ushort)(u >> 16);
}
__device__ __forceinline__ float bf2f(ushort u) {
  union { unsigned u; float f; } v; v.u = (unsigned)u << 16;
  return v.f;
}

// raw barrier: lgkmcnt(0) for LDS visibility, NO vmcnt drain.
__device__ __forceinline__ void waitbar() {
  asm volatile("s_waitcnt lgkmcnt(0)" ::: "memory");
  __builtin_amdgcn_s_barrier();
  __builtin_amdgcn_sched_barrier(0);
}

// G4-standard swizzle for 128B rows (r17/r19-proven, 0 conflicts measured):
__device__ __forceinline__ int sw128(int row, int slot) {
  return row * 128 + ((slot * 16) ^ ((row & 7) << 4));
}

// ---------------------------------------------------------------------------
// Kernel 0: Wq/Wk/Wv fp32 [1024][128] -> bf16 wt, FRAGMENT-LINEAR per
// (kt, half): wt[((kt*2+half)*24 + fs)*512 + lane*8 + j] holds
//   B col gc = half*192 + (fs%12)*16 + (lane&15),
//   k      c = kt*64 + (fs/12)*32 + (lane>>4)*8 + j.
// A wave's B-fragment = ONE contiguous 1 KB read (L2-resident).
// ---------------------------------------------------------------------------
__global__ void wt_convert(const float* __restrict__ Wq,
                           const float* __restrict__ Wk,
                           const float* __restrict__ Wv,
                           ushort* __restrict__ wt) {
  int o = blockIdx.x * 256 + threadIdx.x;   // 0..393215
  int kthalf = o / 12288;                    // 0..31
  int rem = o - kthalf * 12288;
  int fs = rem >> 9;                         // 0..23
  int li = rem & 511;
  int lane = li >> 3, j = li & 7;
  int kt = kthalf >> 1, half = kthalf & 1;
  int kk = fs / 12, cg = fs - kk * 12;
  int gc = half * 192 + cg * 16 + (lane & 15);
  int c  = kt * 64 + kk * 32 + (lane >> 4) * 8 + j;
  int mat = gc >> 7, h = gc & 127;
  const float* W = (mat == 0) ? Wq : ((mat == 1) ? Wk : Wv);
  wt[o] = f2bf(W[c * H_DIM + h]);
}

// ---------------------------------------------------------------------------
// Kernel 1: fused QKV projection v12 = v11 (inline-B from L2) with BM=32.
//  - Grid 1024 -> 4 blocks/CU, 16 waves/CU (the occupancy v11 lacked).
//  - B fragments loaded INLINE at MFMA site (1 KB contiguous, L2-resident,
//    no prefetch registers to collapse, 0 conflicts).
//  - A via LDS (2x4 KB dbuf, sw128 swizzle, E/O distance-2, raw barrier).
//  - A-frag loads identical across the block's 4 waves -> L1 broadcast.
//  - BM=32, BN=192, BK=64 -> 16 iters, 12 MFMA/wave/iter.
// ---------------------------------------------------------------------------
__global__ __launch_bounds__(256, 4) void qkv_gemm(const float* __restrict__ X,
                                                   const ushort* __restrict__ wt,
                                                   ushort* __restrict__ qws,
                                                   ushort* __restrict__ kws,
                                                   ushort* __restrict__ vtws) {
  __shared__ ushort As[2][32 * 64];    // [32][64] sw128, 4 KB each
  const int tid = threadIdx.x;
  const int wid = tid >> 6, lane = tid & 63;
  const int lg = lane >> 4, lr = lane & 15;
  const int m0 = (blockIdx.x >> 1) * 32;
  const int n0h = blockIdx.x & 1;
  const int n0 = n0h * 192;
  const float QSCL = 0.03125f * 1.44269504f;

  // A staging: thread -> row tid>>3 (0..31), 16B slot tid&7 (8 floats)
  const int arow = tid >> 3, aslot = tid & 7;
  const float* gA0 = &X[(size_t)(m0 + arow) * C_DIM + aslot * 8];
  const int awb0 = sw128(arow, aslot);

  // A fragment read bases: rows lr / 16+lr; +2048 for r=1
  const int afb0 = sw128(lr, lg), afb1 = sw128(lr, 4 + lg);

  // B fragment base (per-lane): fragment (kt, kk, c) at
  //   wt + ((kt*2+n0h)*24 + kk*12 + wid*3 + c)*512 + lane*8
  const ushort* wB = wt + (size_t)lane * 8 + (size_t)(wid * 3) * 512;

  f32x4 acc[2][3];
#pragma unroll
  for (int r = 0; r < 2; ++r)
#pragma unroll
    for (int c = 0; c < 3; ++c)
      acc[r][c] = f32x4{0.f, 0.f, 0.f, 0.f};

  float4 aE[2], aO[2];

#define LOAD_A(aS, kt_)                                                    \
  {                                                                        \
    aS[0] = *(const float4*)(gA0 + (kt_) * 64);                            \
    aS[1] = *(const float4*)(gA0 + (kt_) * 64 + 4);                        \
  }
#define WRITE_A(aS, buf)                                                   \
  {                                                                        \
    us8 av0;                                                               \
    av0[0] = f2bf(aS[0].x); av0[1] = f2bf(aS[0].y);                        \
    av0[2] = f2bf(aS[0].z); av0[3] = f2bf(aS[0].w);                        \
    av0[4] = f2bf(aS[1].x); av0[5] = f2bf(aS[1].y);                        \
    av0[6] = f2bf(aS[1].z); av0[7] = f2bf(aS[1].w);                        \
    *(us8*)((char*)&As[buf][0] + awb0) = av0;                              \
  }
#define COMPUTE(buf, kt_)                                                  \
  {                                                                        \
    const ushort* wBk = wB + (size_t)(((kt_) * 2 + n0h) * 24) * 512;       \
    _Pragma("unroll")                                                      \
    for (int kk = 0; kk < 2; ++kk) {                                       \
      const int afb = kk ? afb1 : afb0;                                    \
      bf16x8 b0 = *(const bf16x8*)(wBk + (size_t)(kk * 12) * 512);         \
      bf16x8 b1 = *(const bf16x8*)(wBk + (size_t)(kk * 12 + 1) * 512);     \
      bf16x8 b2 = *(const bf16x8*)(wBk + (size_t)(kk * 12 + 2) * 512);     \
      bf16x8 a0 = *(const bf16x8*)((const char*)&As[buf][0] + afb);        \
      bf16x8 a1 = *(const bf16x8*)((const char*)&As[buf][0] + afb + 2048); \
      acc[0][0] = MFMA(a0, b0, acc[0][0]);                                 \
      acc[1][0] = MFMA(a1, b0, acc[1][0]);                                 \
      acc[0][1] = MFMA(a0, b1, acc[0][1]);                                 \
      acc[1][1] = MFMA(a1, b1, acc[1][1]);                                 \
      acc[0][2] = MFMA(a0, b2, acc[0][2]);                                 \
      acc[1][2] = MFMA(a1, b2, acc[1][2]);                                 \
    }                                                                      \
  }

  // ---- prologue: A(0) -> buf0; A(1)->E, A(2)->O ----
  {
    float4 aT[2];
    LOAD_A(aT, 0);
    WRITE_A(aT, 0);
  }
  LOAD_A(aE, 1);
  LOAD_A(aO, 2);
  waitbar();   // tile0 staged & visible

  for (int k2 = 0; k2 < 16; k2 += 2) {
    // ==== even iter kt=k2: write A(k2+1) -> buf1; compute buf0 ====
    WRITE_A(aE, 1);
    if (k2 + 3 < 16) LOAD_A(aE, k2 + 3);
    COMPUTE(0, k2);
    waitbar();

    // ==== odd iter kt=k2+1: write A(k2+2) -> buf0; compute buf1 ====
    if (k2 + 2 < 16) WRITE_A(aO, 0);
    if (k2 + 4 < 16) LOAD_A(aO, k2 + 4);
    COMPUTE(1, k2 + 1);
    waitbar();
  }
#undef LOAD_A
#undef WRITE_A
#undef COMPUTE

  // epilogue: C frag layout col=lane&15, row=(lane>>4)*4+j
#pragma unroll
  for (int c = 0; c < 3; ++c) {
    int gc = n0 + wid * 48 + c * 16 + lr;
    int mat = gc >> 7, h = gc & 127;
#pragma unroll
    for (int r = 0; r < 2; ++r) {
#pragma unroll
      for (int j = 0; j < 4; ++j) {
        int gr = m0 + r * 16 + lg * 4 + j;
        float val = acc[r][c][j];
        ushort ov = f2bf(mat == 0 ? val * QSCL : val);
        if (mat == 0) {
          qws[(size_t)gr * H_DIM + h] = ov;
        } else if (mat == 1) {
          kws[(size_t)gr * H_DIM + h] = ov;
        } else {
          int b = gr >> 11, t = gr & 2047;
          vtws[((size_t)b * H_DIM + h) * T_LEN + t] = ov;
        }
      }
    }
  }
}

// ---------------------------------------------------------------------------
// Kernel 2a: flash partial pass, block-cooperative LDS-staged K/V
// (unchanged from round 9).
// ---------------------------------------------------------------------------
__global__ __launch_bounds__(256, 3) void attn_part(const ushort* __restrict__ qws,
                                                    const ushort* __restrict__ kws,
                                                    const ushort* __restrict__ vtws,
                                                    float* __restrict__ pml,
                                                    ushort* __restrict__ pacc,
                                                    float* __restrict__ out) {
  __shared__ ushort Klds[64 * KSTR];
  __shared__ ushort Vlds[128 * VSTR];
  __shared__ ushort Pw[4][16 * PSTR];

  const int tid = threadIdx.x;
  const int wid = tid >> 6, lane = tid & 63;
  const int lg = lane >> 4, lr = lane & 15;
  const int bid = blockIdx.x;
  const int b = bid & 7;
  const int item = bid >> 3;

  int qb, ck;
  bool direct;
  if (item < 8) {
    qb = item; ck = 0; direct = true;
  } else {
    const int p = item - 8;
    direct = false;
    if (p < 12)      { int q = p / 3;        qb = 8 + q;  ck = p - q * 3; }
    else if (p < 28) { int q = (p - 12) >> 2; qb = 12 + q; ck = (p - 12) & 3; }
    else if (p < 48) { int q = (p - 28) / 5; qb = 16 + q; ck = (p - 28) - q * 5; }
    else if (p < 72) { int q = (p - 48) / 6; qb = 20 + q; ck = (p - 48) - q * 6; }
    else if (p < 100){ int q = (p - 72) / 7; qb = 24 + q; ck = (p - 72) - q * 7; }
    else             { int q = (p - 100) >> 3; qb = 28 + q; ck = (p - 100) & 7; }
  }
  const int qi = qb * 4 + wid;
  const int q0 = qi * 16;
  const int nt = qb + 1;
  const int kvt_lo = direct ? 0 : ck * 4;
  const int kvt_hi = direct ? nt : min(ck * 4 + 4, nt);
  const size_t tokbase = (size_t)b * T_LEN;
  const ushort* vb = vtws + (size_t)b * H_DIM * T_LEN;

  const int kr = tid >> 2, kseg = tid & 3;
  const int vr = tid >> 1, vseg = tid & 1;
  const ushort* gK = &kws[(tokbase + kr) * H_DIM + kseg * 32];
  const ushort* gV = &vb[(size_t)vr * T_LEN + vseg * 32];

  bf16x8 qf[4];
#pragma unroll
  for (int hk = 0; hk < 4; ++hk)
    qf[hk] = *(const bf16x8*)&qws[(tokbase + q0 + lr) * H_DIM + hk * 32 + lg * 8];

  f32x4 acc[8];
#pragma unroll
  for (int hf = 0; hf < 8; ++hf) acc[hf] = f32x4{0.f, 0.f, 0.f, 0.f};
  float mrun = -INFINITY, lrun = 0.f;

  ushort* Pme = &Pw[wid][0];

  us8 kreg[4], vreg[4];
#pragma unroll
  for (int i = 0; i < 4; ++i) {
    kreg[i] = *(const us8*)(gK + (size_t)kvt_lo * 64 * H_DIM + i * 8);
    vreg[i] = *(const us8*)(gV + kvt_lo * 64 + i * 8);
  }

  for (int kvt = kvt_lo; kvt < kvt_hi; ++kvt) {
    const int kv0 = kvt * 64;

    __syncthreads();
#pragma unroll
    for (int i = 0; i < 4; ++i) {
      *(us8*)&Klds[kr * KSTR + kseg * 32 + i * 8] = kreg[i];
      *(us8*)&Vlds[vr * VSTR + vseg * 32 + i * 8] = vreg[i];
    }
    if (kvt + 1 < kvt_hi) {
#pragma unroll
      for (int i = 0; i < 4; ++i) {
        kreg[i] = *(const us8*)(gK + (size_t)(kv0 + 64) * H_DIM + i * 8);
        vreg[i] = *(const us8*)(gV + kv0 + 64 + i * 8);
      }
    }
    __syncthreads();

    f32x4 s[4];
#pragma unroll
    for (int c = 0; c < 4; ++c) {
      f32x4 sc = f32x4{0.f, 0.f, 0.f, 0.f};
#pragma unroll
      for (int hk = 0; hk < 4; ++hk) {
        bf16x8 kf = *(const bf16x8*)&Klds[(c * 16 + lr) * KSTR + hk * 32 + lg * 8];
        sc = MFMA(kf, qf[hk], sc);
      }
      s[c] = sc;
    }

    if (kvt == nt - 1) {
#pragma unroll
      for (int c = 0; c < 4; ++c)
#pragma unroll
        for (int j = 0; j < 4; ++j) {
          int kv = kv0 + c * 16 + lg * 4 + j;
          if (kv > q0 + lr) s[c][j] = -INFINITY;
        }
    }

    float mx = s[0][0];
#pragma unroll
    for (int c = 0; c < 4; ++c)
#pragma unroll
      for (int j = 0; j < 4; ++j) mx = fmaxf(mx, s[c][j]);
    mx = fmaxf(mx, __shfl_xor(mx, 16));
    mx = fmaxf(mx, __shfl_xor(mx, 32));

    float mnew = fmaxf(mrun, mx);
    float scold = exp2f(mrun - mnew);

    float rsum = 0.f;
#pragma unroll
    for (int c = 0; c < 4; ++c)
#pragma unroll
      for (int j = 0; j < 4; ++j) {
        float p = exp2f(s[c][j] - mnew);
        s[c][j] = p;
        rsum += p;
      }

#pragma unroll
    for (int c = 0; c < 4; ++c) {
      ushort4 u;
      u.x = f2bf(s[c][0]); u.y = f2bf(s[c][1]);
      u.z = f2bf(s[c][2]); u.w = f2bf(s[c][3]);
      *(ushort4*)&Pme[lr * PSTR + c * 16 + lg * 4] = u;
    }

    bf16x8 v0[8];
#pragma unroll
    for (int hf = 0; hf < 8; ++hf)
      v0[hf] = *(const bf16x8*)&Vlds[(hf * 16 + lr) * VSTR + lg * 8];

    rsum += __shfl_xor(rsum, 16);
    rsum += __shfl_xor(rsum, 32);

    lrun = lrun * scold + rsum;
    mrun = mnew;
#pragma unroll
    for (int hf = 0; hf < 8; ++hf)
#pragma unroll
      for (int j = 0; j < 4; ++j) acc[hf][j] *= scold;

    bf16x8 pa0 = *(const bf16x8*)&Pme[lr * PSTR + lg * 8];
    bf16x8 pa1 = *(const bf16x8*)&Pme[lr * PSTR + 32 + lg * 8];

#pragma unroll
    for (int hf = 0; hf < 8; ++hf)
      acc[hf] = MFMA(v0[hf], pa0, acc[hf]);
#pragma unroll
    for (int hf = 0; hf < 8; ++hf) {
      bf16x8 v1 = *(const bf16x8*)&Vlds[(hf * 16 + lr) * VSTR + 32 + lg * 8];
      acc[hf] = MFMA(v1, pa1, acc[hf]);
    }
  }

  if (direct) {
    float inv = 1.0f / lrun;
    float* op = &out[(tokbase + q0 + lr) * H_DIM + lg * 4];
#pragma unroll
    for (int hf = 0; hf < 8; ++hf) {
      float4 r0 = make_float4(acc[hf][0] * inv, acc[hf][1] * inv,
                              acc[hf][2] * inv, acc[hf][3] * inv);
      *(float4*)(op + hf * 16) = r0;
    }
  } else {
    int base;
    if (qi < 48)       base = (qi - 32) * 3;
    else if (qi < 64)  base = 48 + (qi - 48) * 4;
    else if (qi < 80)  base = 112 + (qi - 64) * 5;
    else if (qi < 96)  base = 192 + (qi - 80) * 6;
    else if (qi < 112) base = 288 + (qi - 96) * 7;
    else               base = 400 + (qi - 112) * 8;
    const size_t slot = (size_t)b * SLOTS_PER_B + base + ck;
    if (lg == 0) {
      pml[slot * 32 + lr] = mrun;
      pml[slot * 32 + 16 + lr] = lrun;
    }
    ushort* ap = &pacc[slot * 2048 + (size_t)lr * 128 + lg * 4];
#pragma unroll
    for (int hf = 0; hf < 8; ++hf) {
      ushort4 u;
      u.x = f2bf(acc[hf][0]); u.y = f2bf(acc[hf][1]);
      u.z = f2bf(acc[hf][2]); u.w = f2bf(acc[hf][3]);
      *(ushort4*)(ap + hf * 16) = u;
    }
  }
}

// ---------------------------------------------------------------------------
// Kernel 2b: online merge of 3..8 partials per (b, qi) for qi >= 32.
// (unchanged)
// ---------------------------------------------------------------------------
__global__ __launch_bounds__(256) void attn_merge(const float* __restrict__ pml,
                                                  const ushort* __restrict__ pacc,
                                                  float* __restrict__ out) {
  const int bid = blockIdx.x;
  const int b = bid & 7, qi = (bid >> 3) + 32;
  int base, nch;
  if (qi < 48)       { base = (qi - 32) * 3;        nch = 3; }
  else if (qi < 64)  { base = 48 + (qi - 48) * 4;   nch = 4; }
  else if (qi < 80)  { base = 112 + (qi - 64) * 5;  nch = 5; }
  else if (qi < 96)  { base = 192 + (qi - 80) * 6;  nch = 6; }
  else if (qi < 112) { base = 288 + (qi - 96) * 7;  nch = 7; }
  else               { base = 400 + (qi - 112) * 8; nch = 8; }
  const size_t slot0 = (size_t)b * SLOTS_PER_B + base;
  const int tid = threadIdx.x;
  const int r = tid >> 4, c0 = (tid & 15) * 8;

  float mrun = -INFINITY, L = 0.f;
  float o[8];
#pragma unroll
  for (int i = 0; i < 8; ++i) o[i] = 0.f;

  for (int ck = 0; ck < nch; ++ck) {
    const size_t s = slot0 + ck;
    float m = pml[s * 32 + r];
    float l = pml[s * 32 + 16 + r];
    float mn = fmaxf(mrun, m);
    float sc = exp2f(mrun - mn);
    float w  = exp2f(m - mn);
    L = L * sc + w * l;
    const ushort* ap = &pacc[s * 2048 + (size_t)r * 128 + c0];
    ushort4 u0 = *(const ushort4*)ap;
    ushort4 u1 = *(const ushort4*)(ap + 4);
    o[0] = o[0] * sc + w * bf2f(u0.x); o[1] = o[1] * sc + w * bf2f(u0.y);
    o[2] = o[2] * sc + w * bf2f(u0.z); o[3] = o[3] * sc + w * bf2f(u0.w);
    o[4] = o[4] * sc + w * bf2f(u1.x); o[5] = o[5] * sc + w * bf2f(u1.y);
    o[6] = o[6] * sc + w * bf2f(u1.z); o[7] = o[7] * sc + w * bf2f(u1.w);
    mrun = mn;
  }
  float invL = 1.0f / L;
  float4 r0 = make_float4(o[0] * invL, o[1] * invL, o[2] * invL, o[3] * invL);
  float4 r1 = make_float4(o[4] * invL, o[5] * invL, o[6] * invL, o[7] * invL);
  float* op = &out[((size_t)b * T_LEN + qi * 16 + r) * H_DIM + c0];
  *(float4*)op = r0;
  *(float4*)(op + 4) = r1;
}

// ---------------------------------------------------------------------------
// ws layout identical to rounds 8-20 (total 30,670,848 B, proven fit):
//   [0, 786432) wt (dead after qkv_gemm; pml overlaps, 540,672 B)
//   qws / kws / vtws ; pacc = 8*528 slots * 2048 bf16
// ---------------------------------------------------------------------------
extern "C" void kernel_launch(void* const* d_in, const int* in_sizes, int n_in,
                              void* d_out, int out_size, void* d_ws, size_t ws_size,
                              hipStream_t stream) {
  const float* emb = (const float*)d_in[0];
  const float* Wq  = (const float*)d_in[1];
  const float* Wk  = (const float*)d_in[2];
  const float* Wv  = (const float*)d_in[3];
  float* out = (float*)d_out;

  ushort* wt   = (ushort*)d_ws;
  ushort* qws  = wt  + (size_t)N_COLS * C_DIM;
  ushort* kws  = qws + (size_t)M_ROWS * H_DIM;
  ushort* vtws = kws + (size_t)M_ROWS * H_DIM;
  ushort* pacc = vtws + (size_t)8 * H_DIM * T_LEN;
  float*  pml  = (float*)d_ws;   // overlaps dead wt region

  wt_convert<<<(N_COLS * C_DIM) / 256, 256, 0, stream>>>(Wq, Wk, Wv, wt);
  qkv_gemm<<<(M_ROWS / 32) * 2, 256, 0, stream>>>(emb, wt, qws, kws, vtws);
  attn_part<<<8 * 140, 256, 0, stream>>>(qws, kws, vtws, pml, pacc, out);
  attn_merge<<<8 * 96, 256, 0, stream>>>(pml, pacc, out);
}